// Round 1
// baseline (5910.822 us; speedup 1.0000x reference)
//
#include <hip/hip_runtime.h>
#include <math.h>

#define B_ 16
#define T_ 128
#define S_ 256
#define H_ 512
#define M_ 512
#define V_ 32000
#define GRU_WGS 64

// ---------------- embedding gather ----------------
__global__ __launch_bounds__(128) void k_gather(const int* __restrict__ tgt,
    const float* __restrict__ embed, float* __restrict__ x)
{
  const int row = blockIdx.x;          // b*T+t
  const int v = tgt[row];
  const float4* src = (const float4*)(embed + (size_t)v * H_);
  float4* dst = (float4*)(x + (size_t)row * H_);
  dst[threadIdx.x] = src[threadIdx.x];
}

// ---------------- f32 NT GEMM + bias: C[M][N] = A[M][512] * B[N][512]^T + bias[N]
// grid: (N/64, M/64), block 256, each thread 4x4
__global__ __launch_bounds__(256) void k_gemm_nt_bias(const float* __restrict__ A,
    const float* __restrict__ Bm, const float* __restrict__ bias,
    float* __restrict__ C, int N)
{
  __shared__ float As[64][33];
  __shared__ float Bs[64][33];
  const int tid = threadIdx.x;
  const int tm = tid >> 4, tn = tid & 15;
  const float* Ab = A  + (size_t)blockIdx.y * 64 * 512;
  const float* Bb = Bm + (size_t)blockIdx.x * 64 * 512;
  float acc00=0.f,acc01=0.f,acc02=0.f,acc03=0.f;
  float acc10=0.f,acc11=0.f,acc12=0.f,acc13=0.f;
  float acc20=0.f,acc21=0.f,acc22=0.f,acc23=0.f;
  float acc30=0.f,acc31=0.f,acc32=0.f,acc33=0.f;
  for (int k0 = 0; k0 < 512; k0 += 32) {
#pragma unroll
    for (int i = 0; i < 8; ++i) {
      int v = tid + i * 256;
      int row = v >> 5, col = v & 31;
      As[row][col] = Ab[(size_t)row * 512 + k0 + col];
      Bs[row][col] = Bb[(size_t)row * 512 + k0 + col];
    }
    __syncthreads();
#pragma unroll
    for (int kk = 0; kk < 32; ++kk) {
      float a0 = As[tm*4+0][kk], a1 = As[tm*4+1][kk];
      float a2 = As[tm*4+2][kk], a3 = As[tm*4+3][kk];
      float b0 = Bs[tn*4+0][kk], b1 = Bs[tn*4+1][kk];
      float b2 = Bs[tn*4+2][kk], b3 = Bs[tn*4+3][kk];
      acc00 += a0*b0; acc01 += a0*b1; acc02 += a0*b2; acc03 += a0*b3;
      acc10 += a1*b0; acc11 += a1*b1; acc12 += a1*b2; acc13 += a1*b3;
      acc20 += a2*b0; acc21 += a2*b1; acc22 += a2*b2; acc23 += a2*b3;
      acc30 += a3*b0; acc31 += a3*b1; acc32 += a3*b2; acc33 += a3*b3;
    }
    __syncthreads();
  }
  const int mbase = blockIdx.y*64 + tm*4;
  const int nbase = blockIdx.x*64 + tn*4;
  float bj0 = bias[nbase+0], bj1 = bias[nbase+1], bj2 = bias[nbase+2], bj3 = bias[nbase+3];
  float* Cr0 = C + (size_t)(mbase+0)*N + nbase;
  float* Cr1 = C + (size_t)(mbase+1)*N + nbase;
  float* Cr2 = C + (size_t)(mbase+2)*N + nbase;
  float* Cr3 = C + (size_t)(mbase+3)*N + nbase;
  Cr0[0]=acc00+bj0; Cr0[1]=acc01+bj1; Cr0[2]=acc02+bj2; Cr0[3]=acc03+bj3;
  Cr1[0]=acc10+bj0; Cr1[1]=acc11+bj1; Cr1[2]=acc12+bj2; Cr1[3]=acc13+bj3;
  Cr2[0]=acc20+bj0; Cr2[1]=acc21+bj1; Cr2[2]=acc22+bj2; Cr2[3]=acc23+bj3;
  Cr3[0]=acc30+bj0; Cr3[1]=acc31+bj1; Cr3[2]=acc32+bj2; Cr3[3]=acc33+bj3;
}

// ---------------- GRU layer: persistent kernel, 64 WGs x 256 threads
// WG w owns hidden dims [w*8, w*8+8) for ALL 16 batches; W_hh rows in LDS.
// One device barrier per timestep; h double-buffered in ws.
__global__ __launch_bounds__(256) void k_gru(const float* __restrict__ xg,
    const float* __restrict__ Whh, const float* __restrict__ bhh,
    const float* __restrict__ h0, float* __restrict__ out,
    float* __restrict__ hn_out, float* __restrict__ hbuf,
    unsigned int* __restrict__ bar)
{
  __shared__ float Wl[24][516];          // 24 rows (3 gates x 8 dims), padded
  __shared__ float ps[2][3][128];        // partial sums: [khalf][gate][b*8+dl]
  const int lt = threadIdx.x;
  const int dbase = blockIdx.x * 8;
  // stage this WG's 24 W_hh rows into LDS (row g = gate*512 + dbase + dl)
  for (int r = 0; r < 24; ++r) {
    const int gate = r >> 3, dl2 = r & 7;
    const float* src = Whh + (size_t)(gate * 512 + dbase + dl2) * 512;
    for (int k = lt; k < 512; k += 256) Wl[r][k] = src[k];
  }
  __syncthreads();
  const int kh = lt >> 7;          // k-half 0/1
  const int b  = (lt >> 3) & 15;   // batch
  const int dl = lt & 7;           // local dim
  const int k0 = kh << 8;
  for (int t = 0; t < T_; ++t) {
    const float* hprev = (t == 0) ? h0 : (hbuf + (size_t)((t-1)&1) * 8192);
    const float* hb = hprev + b * 512;
    float ar = 0.f, az = 0.f, an = 0.f;
    for (int k = k0; k < k0 + 256; k += 4) {
      float4 hv = *(const float4*)(hb + k);
      float4 wr = *(const float4*)(&Wl[dl][k]);
      float4 wz = *(const float4*)(&Wl[8+dl][k]);
      float4 wn = *(const float4*)(&Wl[16+dl][k]);
      ar += hv.x*wr.x + hv.y*wr.y + hv.z*wr.z + hv.w*wr.w;
      az += hv.x*wz.x + hv.y*wz.y + hv.z*wz.z + hv.w*wz.w;
      an += hv.x*wn.x + hv.y*wn.y + hv.z*wn.z + hv.w*wn.w;
    }
    const int bd = b * 8 + dl;
    ps[kh][0][bd] = ar; ps[kh][1][bd] = az; ps[kh][2][bd] = an;
    __syncthreads();
    if (lt < 128) {
      const int bb = lt >> 3;
      const int dg = dbase + (lt & 7);
      float ghr = ps[0][0][lt] + ps[1][0][lt] + bhh[dg];
      float ghz = ps[0][1][lt] + ps[1][1][lt] + bhh[512+dg];
      float ghn = ps[0][2][lt] + ps[1][2][lt] + bhh[1024+dg];
      const float* xr = xg + (size_t)(bb * T_ + t) * 1536;
      float rr = 1.f/(1.f+expf(-(xr[dg]       + ghr)));
      float zz = 1.f/(1.f+expf(-(xr[512+dg]   + ghz)));
      float nn = tanhf(   xr[1024+dg] + rr*ghn);
      float hp = hprev[(size_t)bb*512 + dg];
      float hnew = (1.f - zz)*nn + zz*hp;
      hbuf[(size_t)(t&1)*8192 + bb*512 + dg] = hnew;
      out[(size_t)(bb*T_ + t)*512 + dg] = hnew;
      if (t == T_-1) hn_out[bb*512 + dg] = hnew;
    }
    if (t < T_-1) {
      __threadfence();
      __syncthreads();
      if (lt == 0) {
        unsigned g = __hip_atomic_load(&bar[1], __ATOMIC_RELAXED, __HIP_MEMORY_SCOPE_AGENT);
        unsigned old = __hip_atomic_fetch_add(&bar[0], 1u, __ATOMIC_ACQ_REL, __HIP_MEMORY_SCOPE_AGENT);
        if (old == GRU_WGS-1u) {
          __hip_atomic_store(&bar[0], 0u, __ATOMIC_RELAXED, __HIP_MEMORY_SCOPE_AGENT);
          __hip_atomic_fetch_add(&bar[1], 1u, __ATOMIC_RELEASE, __HIP_MEMORY_SCOPE_AGENT);
        } else {
          while (__hip_atomic_load(&bar[1], __ATOMIC_ACQUIRE, __HIP_MEMORY_SCOPE_AGENT) == g)
            __builtin_amdgcn_s_sleep(2);
        }
      }
      __syncthreads();
    }
  }
}

// ---------------- attention: one WG per (b,t) row ----------------
__global__ __launch_bounds__(256) void k_attn(const float* __restrict__ y,
    const float* __restrict__ enc, float* __restrict__ aout)
{
  __shared__ float orow[512];
  __shared__ float wbuf[256];
  __shared__ float red[8];
  const int row = blockIdx.x;        // b*T+t
  const int b = row >> 7;
  const int lt = threadIdx.x;
  orow[lt]       = y[(size_t)row*512 + lt];
  orow[lt + 256] = y[(size_t)row*512 + lt + 256];
  __syncthreads();
  // scores: thread lt handles source position s = lt
  const float* er = enc + (size_t)(b*S_ + lt) * 512;
  float acc = 0.f;
  for (int k = 0; k < 512; k += 4) {
    float4 e = *(const float4*)(er + k);
    acc += orow[k]*e.x + orow[k+1]*e.y + orow[k+2]*e.z + orow[k+3]*e.w;
  }
  // block max
  float m = acc;
#pragma unroll
  for (int off = 32; off > 0; off >>= 1) m = fmaxf(m, __shfl_down(m, off));
  if ((lt & 63) == 0) red[lt >> 6] = m;
  __syncthreads();
  float mx = fmaxf(fmaxf(red[0], red[1]), fmaxf(red[2], red[3]));
  float e = expf(acc - mx);
  wbuf[lt] = e;
  float s = e;
#pragma unroll
  for (int off = 32; off > 0; off >>= 1) s += __shfl_down(s, off);
  if ((lt & 63) == 0) red[4 + (lt >> 6)] = s;
  __syncthreads();
  const float inv = 1.f / (red[4] + red[5] + red[6] + red[7]);
  // context: thread lt handles output dims kk, kk+1
  const int kk = lt * 2;
  float c0 = 0.f, c1 = 0.f;
  for (int s2 = 0; s2 < S_; ++s2) {
    float ws = wbuf[s2];
    float2 ev = *(const float2*)(enc + (size_t)(b*S_ + s2)*512 + kk);
    c0 += ws * ev.x; c1 += ws * ev.y;
  }
  aout[(size_t)row*512 + kk]     = orow[kk]     + c0 * inv;
  aout[(size_t)row*512 + kk + 1] = orow[kk + 1] + c1 * inv;
}

extern "C" void kernel_launch(void* const* d_in, const int* in_sizes, int n_in,
                              void* d_out, int out_size, void* d_ws, size_t ws_size,
                              hipStream_t stream)
{
  const int*   tgt    = (const int*)  d_in[0];
  const float* hidden = (const float*)d_in[1];
  const float* enc    = (const float*)d_in[2];
  const float* embed  = (const float*)d_in[3];
  const float* W_ih0  = (const float*)d_in[4];
  const float* W_hh0  = (const float*)d_in[5];
  const float* b_ih0  = (const float*)d_in[6];
  const float* b_hh0  = (const float*)d_in[7];
  const float* W_ih1  = (const float*)d_in[8];
  const float* W_hh1  = (const float*)d_in[9];
  const float* b_ih1  = (const float*)d_in[10];
  const float* b_hh1  = (const float*)d_in[11];
  const float* W_out  = (const float*)d_in[12];
  const float* b_out  = (const float*)d_in[13];
  float* out = (float*)d_out;

  float* ws   = (float*)d_ws;
  float* xbuf = ws;                          // 2048*512   (x, later attn_out)
  float* xg   = ws + 1048576;                // 2048*1536
  float* out0 = xg + 3145728;                // 2048*512
  float* y1   = out0 + 1048576;              // 2048*512
  float* hbuf = y1 + 1048576;                // 2*16*512
  unsigned int* bar = (unsigned int*)(hbuf + 16384);

  const size_t logitsN = (size_t)(B_*T_) * V_;   // 65,536,000
  float* hn = out + logitsN;
  float* cn = hn + (size_t)2*B_*M_ / 2;          // hn is [2][16][512] -> 16384 floats

  hipMemsetAsync(bar, 0, 2*sizeof(unsigned int), stream);
  hipMemsetAsync(cn, 0, (size_t)16384*sizeof(float), stream);   // cn = zeros

  k_gather<<<dim3(B_*T_), dim3(128), 0, stream>>>(tgt, embed, xbuf);
  k_gemm_nt_bias<<<dim3(1536/64, (B_*T_)/64), dim3(256), 0, stream>>>(xbuf, W_ih0, b_ih0, xg, 1536);
  k_gru<<<dim3(GRU_WGS), dim3(256), 0, stream>>>(xg, W_hh0, b_hh0, hidden, out0, hn, hbuf, bar);
  k_gemm_nt_bias<<<dim3(1536/64, (B_*T_)/64), dim3(256), 0, stream>>>(out0, W_ih1, b_ih1, xg, 1536);
  k_gru<<<dim3(GRU_WGS), dim3(256), 0, stream>>>(xg, W_hh1, b_hh1, hidden + 8192, y1, hn + 8192, hbuf, bar);
  k_attn<<<dim3(B_*T_), dim3(256), 0, stream>>>(y1, enc, xbuf);
  k_gemm_nt_bias<<<dim3(V_/64, (B_*T_)/64), dim3(256), 0, stream>>>(xbuf, W_out, b_out, out, V_);
}

// Round 2
// 5559.462 us; speedup vs baseline: 1.0632x; 1.0632x over previous
//
#include <hip/hip_runtime.h>
#include <math.h>

#define B_ 16
#define T_ 128
#define S_ 256
#define H_ 512
#define M_ 512
#define V_ 32000

// ---------------- embedding gather ----------------
__global__ __launch_bounds__(128) void k_gather(const int* __restrict__ tgt,
    const float* __restrict__ embed, float* __restrict__ x)
{
  const int row = blockIdx.x;          // b*T+t
  const int v = tgt[row];
  const float4* src = (const float4*)(embed + (size_t)v * H_);
  float4* dst = (float4*)(x + (size_t)row * H_);
  dst[threadIdx.x] = src[threadIdx.x];
}

// ---------------- f32 NT GEMM + bias: C[M][N] = A[M][512] * B[N][512]^T + bias[N]
__global__ __launch_bounds__(256) void k_gemm_nt_bias(const float* __restrict__ A,
    const float* __restrict__ Bm, const float* __restrict__ bias,
    float* __restrict__ C, int N)
{
  __shared__ float As[64][33];
  __shared__ float Bs[64][33];
  const int tid = threadIdx.x;
  const int tm = tid >> 4, tn = tid & 15;
  const float* Ab = A  + (size_t)blockIdx.y * 64 * 512;
  const float* Bb = Bm + (size_t)blockIdx.x * 64 * 512;
  float acc00=0.f,acc01=0.f,acc02=0.f,acc03=0.f;
  float acc10=0.f,acc11=0.f,acc12=0.f,acc13=0.f;
  float acc20=0.f,acc21=0.f,acc22=0.f,acc23=0.f;
  float acc30=0.f,acc31=0.f,acc32=0.f,acc33=0.f;
  for (int k0 = 0; k0 < 512; k0 += 32) {
#pragma unroll
    for (int i = 0; i < 8; ++i) {
      int v = tid + i * 256;
      int row = v >> 5, col = v & 31;
      As[row][col] = Ab[(size_t)row * 512 + k0 + col];
      Bs[row][col] = Bb[(size_t)row * 512 + k0 + col];
    }
    __syncthreads();
#pragma unroll
    for (int kk = 0; kk < 32; ++kk) {
      float a0 = As[tm*4+0][kk], a1 = As[tm*4+1][kk];
      float a2 = As[tm*4+2][kk], a3 = As[tm*4+3][kk];
      float b0 = Bs[tn*4+0][kk], b1 = Bs[tn*4+1][kk];
      float b2 = Bs[tn*4+2][kk], b3 = Bs[tn*4+3][kk];
      acc00 += a0*b0; acc01 += a0*b1; acc02 += a0*b2; acc03 += a0*b3;
      acc10 += a1*b0; acc11 += a1*b1; acc12 += a1*b2; acc13 += a1*b3;
      acc20 += a2*b0; acc21 += a2*b1; acc22 += a2*b2; acc23 += a2*b3;
      acc30 += a3*b0; acc31 += a3*b1; acc32 += a3*b2; acc33 += a3*b3;
    }
    __syncthreads();
  }
  const int mbase = blockIdx.y*64 + tm*4;
  const int nbase = blockIdx.x*64 + tn*4;
  float bj0 = bias[nbase+0], bj1 = bias[nbase+1], bj2 = bias[nbase+2], bj3 = bias[nbase+3];
  float* Cr0 = C + (size_t)(mbase+0)*N + nbase;
  float* Cr1 = C + (size_t)(mbase+1)*N + nbase;
  float* Cr2 = C + (size_t)(mbase+2)*N + nbase;
  float* Cr3 = C + (size_t)(mbase+3)*N + nbase;
  Cr0[0]=acc00+bj0; Cr0[1]=acc01+bj1; Cr0[2]=acc02+bj2; Cr0[3]=acc03+bj3;
  Cr1[0]=acc10+bj0; Cr1[1]=acc11+bj1; Cr1[2]=acc12+bj2; Cr1[3]=acc13+bj3;
  Cr2[0]=acc20+bj0; Cr2[1]=acc21+bj1; Cr2[2]=acc22+bj2; Cr2[3]=acc23+bj3;
  Cr3[0]=acc30+bj0; Cr3[1]=acc31+bj1; Cr3[2]=acc32+bj2; Cr3[3]=acc33+bj3;
}

// ---------------- fused 2-layer GRU, software-pipelined ----------------
// 128 WGs x 512 threads. WGs [0,64): layer 0, WGs [64,128): layer 1 (one step behind).
// Each WG owns 8 hidden dims for all 16 batches; its 24 W_hh rows live in LDS.
// Layer 1 computes its input gates (W_ih1 . out0[t]) on the fly -> no second GEMM.
// Dependencies via per-step arrival counters + directed one-shot fences.
__global__ __launch_bounds__(512) void k_gru2(
    const float* __restrict__ xg0,
    const float* __restrict__ Whh0, const float* __restrict__ bhh0,
    const float* __restrict__ Wih1, const float* __restrict__ bih1,
    const float* __restrict__ Whh1, const float* __restrict__ bhh1,
    const float* __restrict__ hidden,
    float* __restrict__ out0, float* __restrict__ y1, float* __restrict__ hn,
    unsigned int* __restrict__ ctrA, unsigned int* __restrict__ ctrB)
{
  __shared__ float Wl[24][516];        // this WG's 24 W_hh rows (3 gates x 8 dims)
  __shared__ float ps[4][6][128];      // partials: [k-quarter][gate][b*8+dl]
  const int bid = blockIdx.x;
  const bool isB = bid >= 64;
  const int wg = isB ? bid - 64 : bid;
  const int dbase = wg * 8;
  const int lt = threadIdx.x;
  const float* Whh = isB ? Whh1 : Whh0;
  for (int r = 0; r < 24; ++r) {
    const int gate = r >> 3, dl2 = r & 7;
    const float* src = Whh + (size_t)(gate * 512 + dbase + dl2) * 512;
    for (int k = lt; k < 512; k += 512) Wl[r][k] = src[k];
  }
  __syncthreads();
  const int kq  = lt >> 7;         // k-quarter 0..3
  const int rem = lt & 127;
  const int b   = rem >> 3;        // batch 0..15
  const int dl  = rem & 7;         // local dim 0..7
  const int k0  = kq << 7;
  const float* h0  = hidden + (isB ? 8192 : 0);
  float* ybuf = isB ? y1 : out0;
  const float* urow  = Wih1 + (size_t)(       dbase + dl) * 512;
  const float* uzrow = Wih1 + (size_t)( 512 + dbase + dl) * 512;
  const float* unrow = Wih1 + (size_t)(1024 + dbase + dl) * 512;
  unsigned int* myctr = isB ? ctrB : ctrA;

  for (int t = 0; t < T_; ++t) {
    if (lt == 0) {
      if (isB) {
        while (__hip_atomic_load(&ctrA[t], __ATOMIC_RELAXED, __HIP_MEMORY_SCOPE_AGENT) < 64u)
          __builtin_amdgcn_s_sleep(1);
      }
      if (t > 0) {
        while (__hip_atomic_load(&myctr[t-1], __ATOMIC_RELAXED, __HIP_MEMORY_SCOPE_AGENT) < 64u)
          __builtin_amdgcn_s_sleep(1);
      }
      __builtin_amdgcn_fence(__ATOMIC_ACQUIRE, "agent");
    }
    __syncthreads();

    const float* hb = t ? (ybuf + ((size_t)(b * T_ + t - 1)) * 512 + k0)
                        : (h0 + b * 512 + k0);
    float ar=0.f, az=0.f, an=0.f, xr=0.f, xz=0.f, xn=0.f;
    if (!isB) {
#pragma unroll 8
      for (int i = 0; i < 32; ++i) {
        const int k = k0 + i * 4;
        float4 hv = *(const float4*)(hb + i * 4);
        float4 wr = *(const float4*)&Wl[dl][k];
        float4 wz = *(const float4*)&Wl[8+dl][k];
        float4 wn = *(const float4*)&Wl[16+dl][k];
        ar += hv.x*wr.x + hv.y*wr.y + hv.z*wr.z + hv.w*wr.w;
        az += hv.x*wz.x + hv.y*wz.y + hv.z*wz.z + hv.w*wz.w;
        an += hv.x*wn.x + hv.y*wn.y + hv.z*wn.z + hv.w*wn.w;
      }
    } else {
      const float* ob = out0 + ((size_t)(b * T_ + t)) * 512 + k0;
#pragma unroll 4
      for (int i = 0; i < 32; ++i) {
        const int k = k0 + i * 4;
        float4 hv = *(const float4*)(hb + i * 4);
        float4 ov = *(const float4*)(ob + i * 4);
        float4 wr = *(const float4*)&Wl[dl][k];
        float4 wz = *(const float4*)&Wl[8+dl][k];
        float4 wn = *(const float4*)&Wl[16+dl][k];
        float4 ur = *(const float4*)(urow + k);
        float4 uz = *(const float4*)(uzrow + k);
        float4 un = *(const float4*)(unrow + k);
        ar += hv.x*wr.x + hv.y*wr.y + hv.z*wr.z + hv.w*wr.w;
        az += hv.x*wz.x + hv.y*wz.y + hv.z*wz.z + hv.w*wz.w;
        an += hv.x*wn.x + hv.y*wn.y + hv.z*wn.z + hv.w*wn.w;
        xr += ov.x*ur.x + ov.y*ur.y + ov.z*ur.z + ov.w*ur.w;
        xz += ov.x*uz.x + ov.y*uz.y + ov.z*uz.z + ov.w*uz.w;
        xn += ov.x*un.x + ov.y*un.y + ov.z*un.z + ov.w*un.w;
      }
    }
    ps[kq][0][rem] = ar; ps[kq][1][rem] = az; ps[kq][2][rem] = an;
    if (isB) { ps[kq][3][rem] = xr; ps[kq][4][rem] = xz; ps[kq][5][rem] = xn; }
    __syncthreads();

    if (lt < 128) {
      const int bb = lt >> 3;
      const int dg = dbase + (lt & 7);
      float ghr = ps[0][0][lt]+ps[1][0][lt]+ps[2][0][lt]+ps[3][0][lt];
      float ghz = ps[0][1][lt]+ps[1][1][lt]+ps[2][1][lt]+ps[3][1][lt];
      float ghn = ps[0][2][lt]+ps[1][2][lt]+ps[2][2][lt]+ps[3][2][lt];
      float ixr, ixz, ixn;
      if (!isB) {
        const float* xrow = xg0 + ((size_t)(bb * T_ + t)) * 1536;
        ghr += bhh0[dg]; ghz += bhh0[512+dg]; ghn += bhh0[1024+dg];
        ixr = xrow[dg]; ixz = xrow[512+dg]; ixn = xrow[1024+dg];
      } else {
        ghr += bhh1[dg]; ghz += bhh1[512+dg]; ghn += bhh1[1024+dg];
        ixr = ps[0][3][lt]+ps[1][3][lt]+ps[2][3][lt]+ps[3][3][lt] + bih1[dg];
        ixz = ps[0][4][lt]+ps[1][4][lt]+ps[2][4][lt]+ps[3][4][lt] + bih1[512+dg];
        ixn = ps[0][5][lt]+ps[1][5][lt]+ps[2][5][lt]+ps[3][5][lt] + bih1[1024+dg];
      }
      float rr = 1.f/(1.f+expf(-(ixr+ghr)));
      float zz = 1.f/(1.f+expf(-(ixz+ghz)));
      float nn = tanhf(ixn + rr*ghn);
      float hp = t ? ybuf[((size_t)(bb * T_ + t - 1))*512 + dg] : h0[bb*512 + dg];
      float hnew = (1.f - zz)*nn + zz*hp;
      ybuf[((size_t)(bb * T_ + t))*512 + dg] = hnew;
      if (t == T_-1) hn[(isB ? 8192 : 0) + bb*512 + dg] = hnew;
    }
    __syncthreads();          // drains this WG's vmem stores (compiler waitcnt before barrier)
    if (lt == 0) {
      __builtin_amdgcn_fence(__ATOMIC_RELEASE, "agent");    // flush stores to coherent point
      __hip_atomic_fetch_add(&myctr[t], 1u, __ATOMIC_RELAXED, __HIP_MEMORY_SCOPE_AGENT);
    }
  }
}

// ---------------- attention: one WG per (b,t) row ----------------
__global__ __launch_bounds__(256) void k_attn(const float* __restrict__ y,
    const float* __restrict__ enc, float* __restrict__ aout)
{
  __shared__ float orow[512];
  __shared__ float wbuf[256];
  __shared__ float red[8];
  const int row = blockIdx.x;        // b*T+t
  const int b = row >> 7;
  const int lt = threadIdx.x;
  orow[lt]       = y[(size_t)row*512 + lt];
  orow[lt + 256] = y[(size_t)row*512 + lt + 256];
  __syncthreads();
  const float* er = enc + (size_t)(b*S_ + lt) * 512;
  float acc = 0.f;
  for (int k = 0; k < 512; k += 4) {
    float4 e = *(const float4*)(er + k);
    acc += orow[k]*e.x + orow[k+1]*e.y + orow[k+2]*e.z + orow[k+3]*e.w;
  }
  float m = acc;
#pragma unroll
  for (int off = 32; off > 0; off >>= 1) m = fmaxf(m, __shfl_down(m, off));
  if ((lt & 63) == 0) red[lt >> 6] = m;
  __syncthreads();
  float mx = fmaxf(fmaxf(red[0], red[1]), fmaxf(red[2], red[3]));
  float e = expf(acc - mx);
  wbuf[lt] = e;
  float s = e;
#pragma unroll
  for (int off = 32; off > 0; off >>= 1) s += __shfl_down(s, off);
  if ((lt & 63) == 0) red[4 + (lt >> 6)] = s;
  __syncthreads();
  const float inv = 1.f / (red[4] + red[5] + red[6] + red[7]);
  const int kk = lt * 2;
  float c0 = 0.f, c1 = 0.f;
  for (int s2 = 0; s2 < S_; ++s2) {
    float ws = wbuf[s2];
    float2 ev = *(const float2*)(enc + (size_t)(b*S_ + s2)*512 + kk);
    c0 += ws * ev.x; c1 += ws * ev.y;
  }
  aout[(size_t)row*512 + kk]     = orow[kk]     + c0 * inv;
  aout[(size_t)row*512 + kk + 1] = orow[kk + 1] + c1 * inv;
}

extern "C" void kernel_launch(void* const* d_in, const int* in_sizes, int n_in,
                              void* d_out, int out_size, void* d_ws, size_t ws_size,
                              hipStream_t stream)
{
  const int*   tgt    = (const int*)  d_in[0];
  const float* hidden = (const float*)d_in[1];
  const float* enc    = (const float*)d_in[2];
  const float* embed  = (const float*)d_in[3];
  const float* W_ih0  = (const float*)d_in[4];
  const float* b_ih0  = (const float*)d_in[6];
  const float* b_hh0  = (const float*)d_in[7];
  const float* W_hh0  = (const float*)d_in[5];
  const float* W_ih1  = (const float*)d_in[8];
  const float* W_hh1  = (const float*)d_in[9];
  const float* b_ih1  = (const float*)d_in[10];
  const float* b_hh1  = (const float*)d_in[11];
  const float* W_out  = (const float*)d_in[12];
  const float* b_out  = (const float*)d_in[13];
  float* out = (float*)d_out;

  float* ws   = (float*)d_ws;
  float* xbuf = ws;                          // 2048*512   (x, later attn_out)
  float* xg   = ws + 1048576;                // 2048*1536  (layer-0 input gates)
  float* out0 = xg + 3145728;                // 2048*512
  float* y1   = out0 + 1048576;              // 2048*512
  unsigned int* ctr = (unsigned int*)(y1 + 1048576);   // 2*128 step counters

  const size_t logitsN = (size_t)(B_*T_) * V_;   // 65,536,000
  float* hn = out + logitsN;
  float* cn = hn + 16384;

  hipMemsetAsync(ctr, 0, 2 * T_ * sizeof(unsigned int), stream);
  hipMemsetAsync(cn, 0, (size_t)16384 * sizeof(float), stream);   // cn = zeros

  k_gather<<<dim3(B_*T_), dim3(128), 0, stream>>>(tgt, embed, xbuf);
  k_gemm_nt_bias<<<dim3(1536/64, (B_*T_)/64), dim3(256), 0, stream>>>(xbuf, W_ih0, b_ih0, xg, 1536);
  k_gru2<<<dim3(128), dim3(512), 0, stream>>>(xg, W_hh0, b_hh0, W_ih1, b_ih1, W_hh1, b_hh1,
                                              hidden, out0, y1, hn, ctr, ctr + T_);
  k_attn<<<dim3(B_*T_), dim3(256), 0, stream>>>(y1, enc, xbuf);
  k_gemm_nt_bias<<<dim3(V_/64, (B_*T_)/64), dim3(256), 0, stream>>>(xbuf, W_out, b_out, out, V_);
}